// Round 2
// baseline (133.334 us; speedup 1.0000x reference)
//
#include <hip/hip_runtime.h>

// Smooth_Blk_Edges: x (2,1024,1024,32) fp32, BLK=(16,16), a=1.0.
//
// All three reference passes compose into ONE position-independent local
// stencil. For a block-corner pixel with vertical partner nh, horizontal
// partner nw and diagonal partner nd:
//     out = (7*self + 3*nh + 3*nw + 2*nd) / 15
// (derived: M = S * (C kron R); by symmetry every corner position gets
// weights {self:7, adjacent:3,3, diagonal:2}/15).
// The SAME weights degenerate correctly when offsets are zeroed:
//   edge-only (oh!=0, ow=0): (7+3)/15 = 2/3 self, (3+2)/15 = 1/3 partner  ✓
//   interior  (oh=ow=0):     (7+3+3+2)/15 = 1                              ✓
// -> fully branchless: every thread does 4 loads + 1 weighted sum + 1 store.
// Redundant interior loads are same-address L1 hits (no extra HBM traffic).

namespace {

constexpr int Hh = 1024;
constexpr int Ww = 1024;
constexpr int C4 = 8;            // float4 per pixel (C=32)
constexpr int sW = C4;           // float4 stride for w+1
constexpr int sH = Ww * C4;      // float4 stride for h+1

__global__ __launch_bounds__(256)
void smooth_blk_edges_kernel(const float4* __restrict__ in,
                             float4* __restrict__ out, const int total4) {
    const int stride = gridDim.x * blockDim.x;
    int i = blockIdx.x * blockDim.x + threadIdx.x;

    constexpr float wS = 7.0f / 15.0f;
    constexpr float wA = 3.0f / 15.0f;
    constexpr float wD = 2.0f / 15.0f;

#pragma unroll 4
    for (; i < total4; i += stride) {
        const int pix = i >> 3;                 // /C4
        const int w = pix & (Ww - 1);
        const int h = (pix >> 10) & (Hh - 1);

        const int hm = h & 15;
        const int wm = w & 15;
        // signed float4-offset to the pairing partner (0 if not on a block edge)
        int oh = 0, ow = 0;
        if (hm == 15 && h != Hh - 1) oh = sH;
        else if (hm == 0 && h != 0)  oh = -sH;
        if (wm == 15 && w != Ww - 1) ow = sW;
        else if (wm == 0 && w != 0)  ow = -sW;

        // 4 independent loads -> good MLP; interior: all same address (L1 hit)
        const float4 s  = in[i];
        const float4 nh = in[i + oh];
        const float4 nw = in[i + ow];
        const float4 nd = in[i + oh + ow];

        float4 r;
        r.x = wS * s.x + wA * nh.x + wA * nw.x + wD * nd.x;
        r.y = wS * s.y + wA * nh.y + wA * nw.y + wD * nd.y;
        r.z = wS * s.z + wA * nh.z + wA * nw.z + wD * nd.z;
        r.w = wS * s.w + wA * nh.w + wA * nw.w + wD * nd.w;

        out[i] = r;
    }
}

}  // namespace

extern "C" void kernel_launch(void* const* d_in, const int* in_sizes, int n_in,
                              void* d_out, int out_size, void* d_ws, size_t ws_size,
                              hipStream_t stream) {
    const float4* in = (const float4*)d_in[0];
    float4* out = (float4*)d_out;
    const int total4 = in_sizes[0] / 4;   // 16,777,216
    const int block = 256;
    const int grid = 2048;                // 8 blocks/CU, grid-stride (32 iters/thread)
    smooth_blk_edges_kernel<<<grid, block, 0, stream>>>(in, out, total4);
}

// Round 4
// 83.157 us; speedup vs baseline: 1.6034x; 1.6034x over previous
//
#include <hip/hip_runtime.h>

// Smooth_Blk_Edges: x (2,1024,1024,32) fp32, BLK=(16,16), a=1.0.
//
// The three reference passes compose into one POSITION-INDEPENDENT stencil:
//     out = (7*self + 3*vert + 3*horiz + 2*diag) / 15
// degenerating to 2/3,1/3 on pure edges and identity in the interior.
// R2 lesson: redundant loads cost VMEM issue slots (5 VMEM/elem -> 152us,
// issue-bound). So: load ONLY the needed neighbors (1/2/4 loads), fill the
// rest by register select, then one universal weighted sum.
// Branch shape per wave (wave = 8 pixels of one row):
//   if(oh)  -> wave-uniform (whole-wave skip)
//   if(ow)  -> 8/64 lanes, single masked load
//   corner  -> only on edge rows, 8/64 lanes
// R3 fix: __builtin_nontemporal_store needs a native clang vector type,
// not HIP_vector_type -> use ext_vector_type(4) float alias throughout.

namespace {

typedef float f32x4 __attribute__((ext_vector_type(4)));

constexpr int Hh = 1024;
constexpr int Ww = 1024;
constexpr int C4 = 8;            // f32x4 per pixel (C=32)
constexpr int sW = C4;           // f32x4 stride for w+1
constexpr int sH = Ww * C4;      // f32x4 stride for h+1

__global__ __launch_bounds__(256)
void smooth_blk_edges_kernel(const f32x4* __restrict__ in,
                             f32x4* __restrict__ out, const int total4) {
    const int i = blockIdx.x * blockDim.x + threadIdx.x;
    if (i >= total4) return;

    const int pix = i >> 3;                  // /C4
    const int w = pix & (Ww - 1);
    const int h = (pix >> 10) & (Hh - 1);

    const int hm = h & 15;
    const int wm = w & 15;
    int oh = 0, ow = 0;
    if (hm == 15 && h != Hh - 1) oh = sH;        // wave-uniform
    else if (hm == 0 && h != 0)  oh = -sH;
    if (wm == 15 && w != Ww - 1) ow = sW;
    else if (wm == 0 && w != 0)  ow = -sW;

    const f32x4 s = in[i];
    f32x4 nh = s, nw = s;
    if (oh != 0) nh = in[i + oh];                // wave-uniform branch
    if (ow != 0) nw = in[i + ow];                // 8/64-lane masked load
    f32x4 nd = (oh != 0) ? nh : nw;              // register select, no load
    if (oh != 0 && ow != 0) nd = in[i + oh + ow];// corner only

    constexpr float wS = 7.0f / 15.0f;
    constexpr float wA = 3.0f / 15.0f;
    constexpr float wD = 2.0f / 15.0f;

    const f32x4 r = wS * s + wA * nh + wA * nw + wD * nd;

    __builtin_nontemporal_store(r, &out[i]);     // output never re-read
}

}  // namespace

extern "C" void kernel_launch(void* const* d_in, const int* in_sizes, int n_in,
                              void* d_out, int out_size, void* d_ws, size_t ws_size,
                              hipStream_t stream) {
    const f32x4* in = (const f32x4*)d_in[0];
    f32x4* out = (f32x4*)d_out;
    const int total4 = in_sizes[0] / 4;   // 16,777,216
    const int block = 256;
    const int grid = (total4 + block - 1) / block;
    smooth_blk_edges_kernel<<<grid, block, 0, stream>>>(in, out, total4);
}